// Round 14
// baseline (237.948 us; speedup 1.0000x reference)
//
#include <hip/hip_runtime.h>
#include <stdint.h>

typedef unsigned short u16;
typedef __attribute__((ext_vector_type(4))) float f32x4;
typedef __attribute__((ext_vector_type(4))) unsigned short u16x4;
typedef __attribute__((ext_vector_type(8))) unsigned short u16x8;
typedef __attribute__((ext_vector_type(8))) short s16x8;
typedef __attribute__((ext_vector_type(4))) short s16x4;
typedef __attribute__((ext_vector_type(2))) unsigned int u32x2;

#define DEVI static __device__ __forceinline__

// counted-vmcnt sync primitives (T4) -- used by the GEMMs only
#define VMCNT(n) asm volatile("s_waitcnt vmcnt(" #n ")" ::: "memory")
#define SBAR() __builtin_amdgcn_s_barrier()
#define SCHED0() __builtin_amdgcn_sched_barrier(0)

// f32 -> bf16 round-to-nearest-even
DEVI u16 f2b(float f) {
  union { float f; unsigned u; } v; v.f = f;
  unsigned r = v.u + 0x7fffu + ((v.u >> 16) & 1u);
  return (u16)(r >> 16);
}
DEVI float b2f(u16 b) {
  union { unsigned u; float f; } v; v.u = ((unsigned)b) << 16;
  return v.f;
}

// async global->LDS, 16B per lane. LDS dest must be wave-uniform base + lane*16.
DEVI void gload_lds16(const void* gptr, void* lptr) {
  typedef const __attribute__((address_space(1))) unsigned gq;
  typedef __attribute__((address_space(3))) unsigned lq;
  __builtin_amdgcn_global_load_lds((gq*)(uintptr_t)gptr,
                                   (lq*)(uint32_t)(uintptr_t)lptr, 16, 0, 0);
}

// v_cvt_pk_bf16_f32: lo=bf16(a), hi=bf16(b)
DEVI unsigned cvtpk(float a, float b) {
  unsigned d;
  asm("v_cvt_pk_bf16_f32 %0, %1, %2" : "=v"(d) : "v"(a), "v"(b));
  return d;
}
// 16x16x16 bf16 MFMA
DEVI f32x4 mfma16(s16x4 a, s16x4 b, f32x4 c) {
  f32x4 d;
  asm("v_mfma_f32_16x16x16_bf16 %0, %1, %2, %3" : "=v"(d) : "v"(a), "v"(b), "v"(c));
  return d;
}
// v_exp_f32 is exp2
DEVI float exp2a(float x) {
  float d;
  asm("v_exp_f32 %0, %1" : "=v"(d) : "v"(x));
  return d;
}

// ---------------------------------------------------------------------------
// All f32 -> bf16 conversions in one dispatch (6 segments, hardcoded bounds).
// ---------------------------------------------------------------------------
__global__ __launch_bounds__(256) void cvt_all(
    const float* __restrict__ X, const float* __restrict__ Wqa,
    const float* __restrict__ Wkva, const float* __restrict__ Wqb,
    const float* __restrict__ Wkvb, const float* __restrict__ Wo,
    u16* __restrict__ Xb, u16* __restrict__ W1, u16* __restrict__ Wqbb,
    u16* __restrict__ Wkvbb, u16* __restrict__ Wob) {
  int i = blockIdx.x * 256 + threadIdx.x;
  const int stride = gridDim.x * 256;
  for (; i < 5079040; i += stride) {   // units of f32x4
    const float* s; u16* d; int j;
    if (i < 1572864) {
      if (i < 1048576) { s = X; d = Xb; j = i; }
      else             { s = Wqa; d = W1; j = i - 1048576; }
    } else if (i < 3112960) {
      if (i < 2064384) { s = Wkva; d = W1 + 1024 * 2048; j = i - 1572864; }
      else             { s = Wqb; d = Wqbb; j = i - 2064384; }
    } else {
      if (i < 4030464) { s = Wkvb; d = Wkvbb; j = i - 3112960; }
      else             { s = Wo; d = Wob; j = i - 4030464; }
    }
    f32x4 v = *(const f32x4*)(s + (size_t)j * 4);
    u16x4 o;
    o[0] = f2b(v[0]); o[1] = f2b(v[1]); o[2] = f2b(v[2]); o[3] = f2b(v[3]);
    *(u16x4*)(d + (size_t)j * 4) = o;
  }
}

// ---------------------------------------------------------------------------
// GEMM core: 128x128 tile, BK=64, 4 waves (2x2), T2 swizzle, T4 counted vmcnt.
// gemm_out: depth-3 pipeline; gemm2_fused: depth-2.
// ---------------------------------------------------------------------------
#define GEMM_STAGE(AP, BP, KK, k0, buf)                                        \
  {                                                                            \
    _Pragma("unroll") for (int p = 0; p < 4; ++p) {                            \
      const int c = tid + p * 256;                                             \
      const int row = c >> 3, j = c & 7;                                       \
      gload_lds16(AP + (size_t)(m0 + row) * (KK) + (k0) + ((j ^ (row & 7)) * 8), \
                  &As[buf][c * 8]);                                            \
    }                                                                          \
    _Pragma("unroll") for (int p = 0; p < 4; ++p) {                            \
      const int c = tid + p * 256;                                             \
      const int row = c >> 3, j = c & 7;                                       \
      gload_lds16(BP + (size_t)(n0 + row) * (KK) + (k0) + ((j ^ (row & 7)) * 8), \
                  &Bs[buf][c * 8]);                                            \
    }                                                                          \
  }

#define GEMM_COMPUTE(cur)                                                      \
  _Pragma("unroll") for (int kk = 0; kk < 64; kk += 32) {                      \
    s16x8 af[4], bfr[4];                                                       \
    _Pragma("unroll") for (int i = 0; i < 4; ++i) {                            \
      const int rA = wm * 64 + i * 16 + c15;                                   \
      af[i] = *(const s16x8*)((const char*)&As[cur][0] + rA * 128 +            \
                              (((kk + g * 8) * 2) ^ ((rA & 7) << 4)));         \
    }                                                                          \
    _Pragma("unroll") for (int i = 0; i < 4; ++i) {                            \
      const int rB = wn * 64 + i * 16 + c15;                                   \
      bfr[i] = *(const s16x8*)((const char*)&Bs[cur][0] + rB * 128 +           \
                               (((kk + g * 8) * 2) ^ ((rB & 7) << 4)));        \
    }                                                                          \
    _Pragma("unroll") for (int i = 0; i < 4; ++i)                              \
      _Pragma("unroll") for (int j = 0; j < 4; ++j)                            \
        acc[i][j] = __builtin_amdgcn_mfma_f32_16x16x32_bf16(af[i], bfr[j],     \
                                                            acc[i][j], 0, 0, 0); \
  }

#define GEMM_PROLOG                                                            \
  const int tid = threadIdx.x;                                                 \
  const int lane = tid & 63, w = tid >> 6;                                     \
  const int wm = w >> 1, wn = w & 1;                                           \
  const int c15 = lane & 15, g = lane >> 4;                                    \
  const int m0 = blockIdx.y * 128, n0 = blockIdx.x * 128;                      \
  f32x4 acc[4][4] = {};

// depth-2 (gemm2_fused)
#define GEMM_LOOP(AP, BP, KK)                                                  \
  GEMM_STAGE(AP, BP, KK, 0, 0);                                                \
  const int nk = (KK) >> 6;                                                    \
  for (int kt = 0; kt < nk; ++kt) {                                            \
    const int cur = kt & 1;                                                    \
    if (kt + 1 < nk) {                                                         \
      GEMM_STAGE(AP, BP, KK, (kt + 1) << 6, cur ^ 1);                          \
      VMCNT(8);                                                                \
    } else {                                                                   \
      VMCNT(0);                                                                \
    }                                                                          \
    SBAR(); SCHED0();                                                          \
    GEMM_COMPUTE(cur);                                                         \
    SBAR(); SCHED0();                                                          \
  }

// depth-3 (gemm_out; requires nk >= 2)
#define GEMM_LOOP3(AP, BP, KK)                                                 \
  GEMM_STAGE(AP, BP, KK, 0, 0);                                                \
  GEMM_STAGE(AP, BP, KK, 64, 1);                                               \
  const int nk = (KK) >> 6;                                                    \
  int bufc = 0;                                                                \
  for (int kt = 0; kt < nk; ++kt) {                                            \
    const int nxt = (bufc + 2 >= 3) ? bufc - 1 : bufc + 2;                     \
    if (kt + 2 < nk) {                                                         \
      GEMM_STAGE(AP, BP, KK, (kt + 2) << 6, nxt);                              \
      VMCNT(16);                                                               \
    } else if (kt + 1 < nk) {                                                  \
      VMCNT(8);                                                                \
    } else {                                                                   \
      VMCNT(0);                                                                \
    }                                                                          \
    SBAR(); SCHED0();                                                          \
    GEMM_COMPUTE(bufc);                                                        \
    SBAR(); SCHED0();                                                          \
    bufc = (bufc + 1 == 3) ? 0 : bufc + 1;                                     \
  }

// GEMM: OUT_BF16=1 writes u16, else f32.
template <int OUT_BF16>
__global__ __launch_bounds__(256) void gemm_out(const u16* __restrict__ A,
                                                const u16* __restrict__ B,
                                                void* __restrict__ Cv,
                                                int M, int N, int K) {
  __shared__ __align__(16) u16 As[3][128 * 64];
  __shared__ __align__(16) u16 Bs[3][128 * 64];
  GEMM_PROLOG
  GEMM_LOOP3(A, B, K)
#pragma unroll
  for (int i = 0; i < 4; ++i)
#pragma unroll
    for (int j = 0; j < 4; ++j) {
      const int mr = m0 + wm * 64 + i * 16 + g * 4;
      const int nc = n0 + wn * 64 + j * 16 + c15;
#pragma unroll
      for (int r = 0; r < 4; ++r) {
        if (OUT_BF16)
          ((u16*)Cv)[(size_t)(mr + r) * N + nc] = f2b(acc[i][j][r]);
        else
          ((float*)Cv)[(size_t)(mr + r) * N + nc] = acc[i][j][r];
      }
    }
}

// ---------------------------------------------------------------------------
// Fused GEMM2: z=0 -> qraw = qn @ Wqb^T (bf16, N=4096);
//              z=1 -> kv = kvn @ Wkvb^T, scatter into PLAIN Kb/Vt (no swizzle
//              -- attn reads K/V direct from L2 now, no LDS staging).
// ---------------------------------------------------------------------------
__global__ __launch_bounds__(256) void gemm2_fused(
    const u16* __restrict__ qn, const u16* __restrict__ Wqbb,
    const u16* __restrict__ kvn, const u16* __restrict__ Wkvbb,
    u16* __restrict__ qraw, char* __restrict__ KbB, char* __restrict__ VtB) {
  __shared__ __align__(16) u16 As[2][128 * 64];
  __shared__ __align__(16) u16 Bs[2][128 * 64];
  const int z = blockIdx.z;
  const u16* A = z ? kvn : qn;
  const u16* B = z ? Wkvbb : Wqbb;
  const int K = z ? 896 : 1024;
  GEMM_PROLOG
  GEMM_LOOP(A, B, K)

  if (z == 0) {
#pragma unroll
    for (int i = 0; i < 4; ++i)
#pragma unroll
      for (int j = 0; j < 4; ++j) {
        const int mr = m0 + wm * 64 + i * 16 + g * 4;
        const int nc = n0 + wn * 64 + j * 16 + c15;
#pragma unroll
        for (int r = 0; r < 4; ++r)
          qraw[(size_t)(mr + r) * 4096 + nc] = f2b(acc[i][j][r]);
      }
  } else {
    const int h = n0 >> 7;  // 128-col tile == one head
#pragma unroll
    for (int i = 0; i < 4; ++i)
#pragma unroll
      for (int j = 0; j < 4; ++j) {
        const int mr = m0 + wm * 64 + i * 16 + g * 4;  // s0 (mult of 4)
        if (wn == 0) {
          const int d = j * 16 + c15;                  // k_nope col
#pragma unroll
          for (int r = 0; r < 4; ++r) {
            const int s = mr + r;
            *(u16*)(KbB + ((size_t)(h * 2048 + s) << 8) + 2 * d) = f2b(acc[i][j][r]);
          }
        } else {
          const int d = j * 16 + c15;                  // value col (0..63)
          u16x4 o;
#pragma unroll
          for (int r = 0; r < 4; ++r) o[r] = f2b(acc[i][j][r]);
          *(u16x4*)(VtB + ((size_t)(h * 64 + d) << 12) + 2 * mr) = o;
        }
      }
  }
}

// ---------------------------------------------------------------------------
// Per-row (C1 in bf16): RMSNorm(q_a)->qn, RMSNorm(ckv)->kvn, RoPE(k_rope)->
// broadcast into Kb[h][s][64:128] (plain layout) for all 32 heads.
// ---------------------------------------------------------------------------
DEVI float block_sum(float v, float* sbuf, int tid) {
#pragma unroll
  for (int o = 32; o; o >>= 1) v += __shfl_xor(v, o, 64);
  __syncthreads();
  if ((tid & 63) == 0) sbuf[tid >> 6] = v;
  __syncthreads();
  return sbuf[0] + sbuf[1] + sbuf[2] + sbuf[3];
}

__global__ __launch_bounds__(256) void norm_rope(const u16* __restrict__ C1b,
    const float* __restrict__ qw, const float* __restrict__ kw,
    const float* __restrict__ cosb, const float* __restrict__ sinb,
    u16* __restrict__ qn, u16* __restrict__ kvn, char* __restrict__ KbB) {
  __shared__ float sbuf[4];
  __shared__ __align__(16) u16 rv[64];
  const int s = blockIdx.x, tid = threadIdx.x;
  const u16* row = C1b + (size_t)s * 2048;

  u16x4 qv4 = *(const u16x4*)(row + tid * 4);
  float q0 = b2f(qv4[0]), q1 = b2f(qv4[1]), q2 = b2f(qv4[2]), q3 = b2f(qv4[3]);
  float ss = q0*q0 + q1*q1 + q2*q2 + q3*q3;
  ss = block_sum(ss, sbuf, tid);
  const float scale = rsqrtf(ss * (1.f / 1024.f) + 1e-6f);
  {
    f32x4 wv = *(const f32x4*)(qw + tid * 4);
    u16x4 o;
    o[0] = f2b(q0 * scale * wv[0]); o[1] = f2b(q1 * scale * wv[1]);
    o[2] = f2b(q2 * scale * wv[2]); o[3] = f2b(q3 * scale * wv[3]);
    *(u16x4*)(qn + (size_t)s * 1024 + tid * 4) = o;
  }

  float ss2 = 0.f;
  float k0 = 0, k1 = 0, k2 = 0, k3 = 0;
  if (tid < 224) {
    u16x4 kv4 = *(const u16x4*)(row + 1024 + tid * 4);
    k0 = b2f(kv4[0]); k1 = b2f(kv4[1]); k2 = b2f(kv4[2]); k3 = b2f(kv4[3]);
    ss2 = k0*k0 + k1*k1 + k2*k2 + k3*k3;
  }
  ss2 = block_sum(ss2, sbuf, tid);
  const float sc2 = rsqrtf(ss2 * (1.f / 896.f) + 1e-6f);
  if (tid < 224) {
    f32x4 wv = *(const f32x4*)(kw + tid * 4);
    u16x4 o;
    o[0] = f2b(k0 * sc2 * wv[0]); o[1] = f2b(k1 * sc2 * wv[1]);
    o[2] = f2b(k2 * sc2 * wv[2]); o[3] = f2b(k3 * sc2 * wv[3]);
    *(u16x4*)(kvn + (size_t)s * 896 + tid * 4) = o;
  }

  if (tid < 64) {
    const int d = tid;
    const float x = b2f(row[1920 + d]);
    const float part = b2f(row[1920 + (d < 32 ? d + 32 : d - 32)]);
    const float cv = cosb[s * 64 + d], sv = sinb[s * 64 + d];
    rv[d] = f2b(d < 32 ? (x * cv - part * sv) : (x * cv + part * sv));
  }
  __syncthreads();
  {
    const int h = tid >> 3, c8 = tid & 7;
    const u16x8 v = *(const u16x8*)&rv[c8 * 8];
    *(u16x8*)(KbB + ((size_t)(h * 2048 + s) << 8) + 128 + c8 * 16) = v;
  }
}

// ---------------------------------------------------------------------------
// Causal flash attention v12: NO LDS, NO BARRIERS. K/V are L2-resident
// (3MB/XCD < 4MB L2); each wave loads its MFMA fragments directly from
// global. 1024 blocks x 128 thr (2 waves; both waves share tiles -> L1
// reuse). Each wave: 32 q rows (2 B-frags per K-frag). Waves free-run --
// latency hidden by co-resident waves + upfront load issue per tile.
// Balanced qt permutation: CU round-robin groups {31-a, a, 23-a, 8+a}
// sum to 62 tiles; LPT (big chains dispatched first).
// ---------------------------------------------------------------------------
__global__ __launch_bounds__(128) void attn_fwd(
    const u16* __restrict__ Qb, const u16* __restrict__ Kb,
    const u16* __restrict__ Vt, const float* __restrict__ cosb,
    const float* __restrict__ sinb, u16* __restrict__ attnb) {
  const int tid = threadIdx.x;
  const int lane = tid & 63, w = tid >> 6;     // w = 0,1
  const int c15 = lane & 15, g = lane >> 4;
  const int orig = blockIdx.x;                 // 1024 blocks
  const int xcd = orig & 7, l = orig >> 3;     // 128 per XCD chunk
  const int h = xcd * 4 + (l & 3);
  const int i4 = l >> 2;                       // 0..31
  const int qt = (i4 < 8) ? 31 - i4 : (i4 < 16) ? i4 - 8
               : (i4 < 24) ? 39 - i4 : i4 - 16;   // balanced + LPT
  const int wmin = qt * 64 + w * 32;           // wave's lowest q row
  const char* KbHB = (const char*)Kb + ((size_t)h << 19);   // h*2048*256
  const char* VtHB = (const char*)Vt + ((size_t)h << 18);   // h*64*4096
  const float SC2 = 0.12753860478587782f;  // (HD+MD)^-0.5 * log2(e)

  // Q fragments for 2 q-subtiles (B operand, k=d), scaled, RoPE on d>=64
  s16x8 qf[2][4];
#pragma unroll
  for (int qa = 0; qa < 2; ++qa) {
    const int qrow = wmin + qa * 16 + c15;
    const u16* qp = Qb + (size_t)qrow * 4096 + h * 128;
    u16x8 x0 = *(const u16x8*)(qp + g * 8);
    u16x8 x1 = *(const u16x8*)(qp + 32 + g * 8);
    u16x8 x2 = *(const u16x8*)(qp + 64 + g * 8);
    u16x8 x3 = *(const u16x8*)(qp + 96 + g * 8);
    const float* cb = cosb + (size_t)qrow * 64 + g * 8;
    const float* sb = sinb + (size_t)qrow * 64 + g * 8;
#pragma unroll
    for (int i = 0; i < 8; ++i) {
      qf[qa][0][i] = (short)f2b(b2f(x0[i]) * SC2);
      qf[qa][1][i] = (short)f2b(b2f(x1[i]) * SC2);
      const float f2 = b2f(x2[i]), f3 = b2f(x3[i]);
      qf[qa][2][i] = (short)f2b((f2 * cb[i] - f3 * sb[i]) * SC2);
      qf[qa][3][i] = (short)f2b((f3 * cb[32 + i] + f2 * sb[32 + i]) * SC2);
    }
  }

  const int nt = qt + 1;
  f32x4 acc[2][4] = {};
  float m[2] = {-1e9f, -1e9f}, ssum[2] = {0.f, 0.f};

  for (int t = 0; t < nt; ++t) {
    const int kv0 = t << 6;

    // issue ALL K fragment loads up front (latency overlaps across them)
    s16x8 kf[4][4];
#pragma unroll
    for (int kvh = 0; kvh < 4; ++kvh) {
      const char* rp = KbHB + (size_t)(kv0 + kvh * 16 + c15) * 256 + g * 16;
#pragma unroll
      for (int d0 = 0; d0 < 4; ++d0)
        kf[kvh][d0] = *(const s16x8*)(rp + d0 * 64);
    }
    // V fragment loads issued early too (independent of softmax)
    s16x4 vf[4][4];
#pragma unroll
    for (int dt = 0; dt < 4; ++dt) {
      const char* vp = VtHB + (size_t)(dt * 16 + c15) * 4096 + 2 * (kv0 + g * 4);
#pragma unroll
      for (int ks = 0; ks < 4; ++ks)
        vf[dt][ks] = *(const s16x4*)(vp + ks * 32);
    }

    float pv[2][4][4];
    __builtin_amdgcn_s_setprio(1);
#pragma unroll
    for (int kvh = 0; kvh < 4; ++kvh) {
#pragma unroll
      for (int qa = 0; qa < 2; ++qa) {
        f32x4 s4 = {};
#pragma unroll
        for (int d0 = 0; d0 < 4; ++d0)
          s4 = __builtin_amdgcn_mfma_f32_16x16x32_bf16(kf[kvh][d0], qf[qa][d0], s4, 0, 0, 0);
        pv[qa][kvh][0] = s4[0]; pv[qa][kvh][1] = s4[1];
        pv[qa][kvh][2] = s4[2]; pv[qa][kvh][3] = s4[3];
      }
    }
    __builtin_amdgcn_s_setprio(0);

    if (kv0 + 63 > wmin) {  // diagonal region for this wave
#pragma unroll
      for (int qa = 0; qa < 2; ++qa) {
        const int qrow = wmin + qa * 16 + c15;
#pragma unroll
        for (int kvh = 0; kvh < 4; ++kvh)
#pragma unroll
          for (int r = 0; r < 4; ++r) {
            const int kv = kv0 + kvh * 16 + g * 4 + r;
            if (kv > qrow) pv[qa][kvh][r] = -1e9f;
          }
      }
    }

    s16x4 pB[2][4];
#pragma unroll
    for (int qa = 0; qa < 2; ++qa) {
      // per-lane partial max; full cross-lane reduce only when needed
      float pml = -1e9f;
#pragma unroll
      for (int kvh = 0; kvh < 4; ++kvh)
#pragma unroll
        for (int r = 0; r < 4; ++r) pml = fmaxf(pml, pv[qa][kvh][r]);
      if (!__all(pml - m[qa] <= 8.f)) {     // pm-defer (T13 extended)
        float pm = fmaxf(pml, __shfl_xor(pml, 16, 64));
        pm = fmaxf(pm, __shfl_xor(pm, 32, 64));
        const float mnew = fmaxf(m[qa], pm);
        const float alpha = exp2a(m[qa] - mnew);
        ssum[qa] *= alpha;
#pragma unroll
        for (int dt = 0; dt < 4; ++dt) acc[qa][dt] *= alpha;
        m[qa] = mnew;
      }
#pragma unroll
      for (int kvh = 0; kvh < 4; ++kvh)
#pragma unroll
        for (int r = 0; r < 4; ++r) {
          const float p = exp2a(pv[qa][kvh][r] - m[qa]);
          pv[qa][kvh][r] = p;
          ssum[qa] += p;
        }
#pragma unroll
      for (int ks = 0; ks < 4; ++ks) {
        u32x2 pw;
        pw[0] = cvtpk(pv[qa][ks][0], pv[qa][ks][1]);
        pw[1] = cvtpk(pv[qa][ks][2], pv[qa][ks][3]);
        pB[qa][ks] = __builtin_bit_cast(s16x4, pw);
      }
    }

    __builtin_amdgcn_s_setprio(1);
#pragma unroll
    for (int dt = 0; dt < 4; ++dt) {
#pragma unroll
      for (int ks = 0; ks < 4; ++ks) {
        acc[0][dt] = mfma16(vf[dt][ks], pB[0][ks], acc[0][dt]);
        acc[1][dt] = mfma16(vf[dt][ks], pB[1][ks], acc[1][dt]);
      }
    }
    __builtin_amdgcn_s_setprio(0);
  }

#pragma unroll
  for (int qa = 0; qa < 2; ++qa) {
    float sv = ssum[qa];
    sv += __shfl_xor(sv, 16, 64);
    sv += __shfl_xor(sv, 32, 64);
    const float inv = 1.f / sv;
    const int qrow = wmin + qa * 16 + c15;
#pragma unroll
    for (int dt = 0; dt < 4; ++dt) {
      u16x4 o;
#pragma unroll
      for (int r = 0; r < 4; ++r) o[r] = f2b(acc[qa][dt][r] * inv);
      *(u16x4*)(attnb + (size_t)qrow * 2048 + h * 64 + dt * 16 + g * 4) = o;
    }
  }
}

// ---------------------------------------------------------------------------
extern "C" void kernel_launch(void* const* d_in, const int* in_sizes, int n_in,
                              void* d_out, int out_size, void* d_ws, size_t ws_size,
                              hipStream_t stream) {
  const float* X    = (const float*)d_in[0];
  const float* cosb = (const float*)d_in[1];
  const float* sinb = (const float*)d_in[2];
  const float* Wqa  = (const float*)d_in[3];
  const float* qlnw = (const float*)d_in[4];
  const float* Wqb  = (const float*)d_in[5];
  const float* Wkva = (const float*)d_in[6];
  const float* klnw = (const float*)d_in[7];
  const float* Wkvb = (const float*)d_in[8];
  const float* Wo   = (const float*)d_in[9];
  float* out = (float*)d_out;
  char* ws = (char*)d_ws;

  // workspace layout (bytes); total 96 MiB
  u16*   Xb     = (u16*)(ws + 0);          // [0,8M)     dies after GEMM1
  u16*   W1     = (u16*)(ws + 8388608);    // [8,16M)    dies after GEMM1
  u16*   C1b    = (u16*)(ws + 16777216);   // [16,24M)   bf16, dies after norm
  u16*   qn     = (u16*)(ws + 33554432);   // [32,36M)
  u16*   kvn    = (u16*)(ws + 37748736);   // [36,39.5M)
  u16*   Wqbb   = (u16*)(ws + 41943040);   // [40,48M)
  u16*   Wkvbb  = (u16*)(ws + 50331648);   // [48,55M)
  u16*   qraw_b = (u16*)(ws + 0);          // [0,16M)  overlays Xb+W1
  u16*   Kb     = (u16*)(ws + 58720256);   // [56,72M)  32h x 2048 x 256B plain
  u16*   VtG    = (u16*)(ws + 75497472);   // [72,80M)  32h x 64 x 4096B plain
  u16*   attnb  = (u16*)(ws + 83886080);   // [80,88M)
  u16*   Wob    = (u16*)(ws + 92274688);   // [88,96M)

  // 1. all f32->bf16 conversions in one dispatch
  cvt_all<<<2048, 256, 0, stream>>>(X, Wqa, Wkva, Wqb, Wkvb, Wo,
                                    Xb, W1, Wqbb, Wkvbb, Wob);

  // 2. C1 = X @ [Wqa;Wkva]^T  (bf16 out)
  gemm_out<1><<<dim3(16, 16), 256, 0, stream>>>(Xb, W1, C1b, 2048, 2048, 2048);

  // 3. RMSNorm + roped-k broadcast into Kb[..][64:128]
  norm_rope<<<2048, 256, 0, stream>>>(C1b, qlnw, klnw, cosb, sinb, qn, kvn, (char*)Kb);

  // 4. fused: qraw_b = qn @ Wqb^T  and  {Kb,Vt} <- kvn @ Wkvb^T
  gemm2_fused<<<dim3(32, 16, 2), 256, 0, stream>>>(qn, Wqbb, kvn, Wkvbb,
                                                   qraw_b, (char*)Kb, (char*)VtG);

  // 5. causal attention: barrier-free, K/V direct from L2
  attn_fwd<<<1024, 128, 0, stream>>>(qraw_b, Kb, VtG, cosb, sinb, attnb);

  // 6. out = attn @ Wo^T  (f32 out)
  gemm_out<0><<<dim3(16, 16), 256, 0, stream>>>(attnb, Wob, out, 2048, 2048, 2048);
}

// Round 15
// 202.055 us; speedup vs baseline: 1.1776x; 1.1776x over previous
//
#include <hip/hip_runtime.h>
#include <stdint.h>

typedef unsigned short u16;
typedef __attribute__((ext_vector_type(4))) float f32x4;
typedef __attribute__((ext_vector_type(4))) unsigned short u16x4;
typedef __attribute__((ext_vector_type(8))) unsigned short u16x8;
typedef __attribute__((ext_vector_type(8))) short s16x8;
typedef __attribute__((ext_vector_type(4))) short s16x4;
typedef __attribute__((ext_vector_type(2))) unsigned int u32x2;

#define DEVI static __device__ __forceinline__

// counted-vmcnt sync primitives (T4)
#define VMCNT(n) asm volatile("s_waitcnt vmcnt(" #n ")" ::: "memory")
#define SBAR() __builtin_amdgcn_s_barrier()
#define SCHED0() __builtin_amdgcn_sched_barrier(0)

// f32 -> bf16 round-to-nearest-even
DEVI u16 f2b(float f) {
  union { float f; unsigned u; } v; v.f = f;
  unsigned r = v.u + 0x7fffu + ((v.u >> 16) & 1u);
  return (u16)(r >> 16);
}
DEVI float b2f(u16 b) {
  union { unsigned u; float f; } v; v.u = ((unsigned)b) << 16;
  return v.f;
}

// async global->LDS, 16B per lane. LDS dest must be wave-uniform base + lane*16.
DEVI void gload_lds16(const void* gptr, void* lptr) {
  typedef const __attribute__((address_space(1))) unsigned gq;
  typedef __attribute__((address_space(3))) unsigned lq;
  __builtin_amdgcn_global_load_lds((gq*)(uintptr_t)gptr,
                                   (lq*)(uint32_t)(uintptr_t)lptr, 16, 0, 0);
}

// v_cvt_pk_bf16_f32: lo=bf16(a), hi=bf16(b)
DEVI unsigned cvtpk(float a, float b) {
  unsigned d;
  asm("v_cvt_pk_bf16_f32 %0, %1, %2" : "=v"(d) : "v"(a), "v"(b));
  return d;
}
// 16x16x16 bf16 MFMA
DEVI f32x4 mfma16(s16x4 a, s16x4 b, f32x4 c) {
  f32x4 d;
  asm("v_mfma_f32_16x16x16_bf16 %0, %1, %2, %3" : "=v"(d) : "v"(a), "v"(b), "v"(c));
  return d;
}
// v_exp_f32 is exp2
DEVI float exp2a(float x) {
  float d;
  asm("v_exp_f32 %0, %1" : "=v"(d) : "v"(x));
  return d;
}

// ---------------------------------------------------------------------------
// All f32 -> bf16 conversions in one dispatch (6 segments, hardcoded bounds).
// ---------------------------------------------------------------------------
__global__ __launch_bounds__(256) void cvt_all(
    const float* __restrict__ X, const float* __restrict__ Wqa,
    const float* __restrict__ Wkva, const float* __restrict__ Wqb,
    const float* __restrict__ Wkvb, const float* __restrict__ Wo,
    u16* __restrict__ Xb, u16* __restrict__ W1, u16* __restrict__ Wqbb,
    u16* __restrict__ Wkvbb, u16* __restrict__ Wob) {
  int i = blockIdx.x * 256 + threadIdx.x;
  const int stride = gridDim.x * 256;
  for (; i < 5079040; i += stride) {   // units of f32x4
    const float* s; u16* d; int j;
    if (i < 1572864) {
      if (i < 1048576) { s = X; d = Xb; j = i; }
      else             { s = Wqa; d = W1; j = i - 1048576; }
    } else if (i < 3112960) {
      if (i < 2064384) { s = Wkva; d = W1 + 1024 * 2048; j = i - 1572864; }
      else             { s = Wqb; d = Wqbb; j = i - 2064384; }
    } else {
      if (i < 4030464) { s = Wkvb; d = Wkvbb; j = i - 3112960; }
      else             { s = Wo; d = Wob; j = i - 4030464; }
    }
    f32x4 v = *(const f32x4*)(s + (size_t)j * 4);
    u16x4 o;
    o[0] = f2b(v[0]); o[1] = f2b(v[1]); o[2] = f2b(v[2]); o[3] = f2b(v[3]);
    *(u16x4*)(d + (size_t)j * 4) = o;
  }
}

// ---------------------------------------------------------------------------
// GEMM core: 128x128 tile, BK=64, 4 waves (2x2), T2 swizzle, T4 counted vmcnt.
// gemm_out: depth-3 pipeline; gemm2_fused: depth-2.
// ---------------------------------------------------------------------------
#define GEMM_STAGE(AP, BP, KK, k0, buf)                                        \
  {                                                                            \
    _Pragma("unroll") for (int p = 0; p < 4; ++p) {                            \
      const int c = tid + p * 256;                                             \
      const int row = c >> 3, j = c & 7;                                       \
      gload_lds16(AP + (size_t)(m0 + row) * (KK) + (k0) + ((j ^ (row & 7)) * 8), \
                  &As[buf][c * 8]);                                            \
    }                                                                          \
    _Pragma("unroll") for (int p = 0; p < 4; ++p) {                            \
      const int c = tid + p * 256;                                             \
      const int row = c >> 3, j = c & 7;                                       \
      gload_lds16(BP + (size_t)(n0 + row) * (KK) + (k0) + ((j ^ (row & 7)) * 8), \
                  &Bs[buf][c * 8]);                                            \
    }                                                                          \
  }

#define GEMM_COMPUTE(cur)                                                      \
  _Pragma("unroll") for (int kk = 0; kk < 64; kk += 32) {                      \
    s16x8 af[4], bfr[4];                                                       \
    _Pragma("unroll") for (int i = 0; i < 4; ++i) {                            \
      const int rA = wm * 64 + i * 16 + c15;                                   \
      af[i] = *(const s16x8*)((const char*)&As[cur][0] + rA * 128 +            \
                              (((kk + g * 8) * 2) ^ ((rA & 7) << 4)));         \
    }                                                                          \
    _Pragma("unroll") for (int i = 0; i < 4; ++i) {                            \
      const int rB = wn * 64 + i * 16 + c15;                                   \
      bfr[i] = *(const s16x8*)((const char*)&Bs[cur][0] + rB * 128 +           \
                               (((kk + g * 8) * 2) ^ ((rB & 7) << 4)));        \
    }                                                                          \
    _Pragma("unroll") for (int i = 0; i < 4; ++i)                              \
      _Pragma("unroll") for (int j = 0; j < 4; ++j)                            \
        acc[i][j] = __builtin_amdgcn_mfma_f32_16x16x32_bf16(af[i], bfr[j],     \
                                                            acc[i][j], 0, 0, 0); \
  }

#define GEMM_PROLOG                                                            \
  const int tid = threadIdx.x;                                                 \
  const int lane = tid & 63, w = tid >> 6;                                     \
  const int wm = w >> 1, wn = w & 1;                                           \
  const int c15 = lane & 15, g = lane >> 4;                                    \
  const int m0 = blockIdx.y * 128, n0 = blockIdx.x * 128;                      \
  f32x4 acc[4][4] = {};

// depth-2 (gemm2_fused)
#define GEMM_LOOP(AP, BP, KK)                                                  \
  GEMM_STAGE(AP, BP, KK, 0, 0);                                                \
  const int nk = (KK) >> 6;                                                    \
  for (int kt = 0; kt < nk; ++kt) {                                            \
    const int cur = kt & 1;                                                    \
    if (kt + 1 < nk) {                                                         \
      GEMM_STAGE(AP, BP, KK, (kt + 1) << 6, cur ^ 1);                          \
      VMCNT(8);                                                                \
    } else {                                                                   \
      VMCNT(0);                                                                \
    }                                                                          \
    SBAR(); SCHED0();                                                          \
    GEMM_COMPUTE(cur);                                                         \
    SBAR(); SCHED0();                                                          \
  }

// depth-3 (gemm_out; requires nk >= 2)
#define GEMM_LOOP3(AP, BP, KK)                                                 \
  GEMM_STAGE(AP, BP, KK, 0, 0);                                                \
  GEMM_STAGE(AP, BP, KK, 64, 1);                                               \
  const int nk = (KK) >> 6;                                                    \
  int bufc = 0;                                                                \
  for (int kt = 0; kt < nk; ++kt) {                                            \
    const int nxt = (bufc + 2 >= 3) ? bufc - 1 : bufc + 2;                     \
    if (kt + 2 < nk) {                                                         \
      GEMM_STAGE(AP, BP, KK, (kt + 2) << 6, nxt);                              \
      VMCNT(16);                                                               \
    } else if (kt + 1 < nk) {                                                  \
      VMCNT(8);                                                                \
    } else {                                                                   \
      VMCNT(0);                                                                \
    }                                                                          \
    SBAR(); SCHED0();                                                          \
    GEMM_COMPUTE(bufc);                                                        \
    SBAR(); SCHED0();                                                          \
    bufc = (bufc + 1 == 3) ? 0 : bufc + 1;                                     \
  }

// GEMM: OUT_BF16=1 writes u16, else f32.
template <int OUT_BF16>
__global__ __launch_bounds__(256) void gemm_out(const u16* __restrict__ A,
                                                const u16* __restrict__ B,
                                                void* __restrict__ Cv,
                                                int M, int N, int K) {
  __shared__ __align__(16) u16 As[3][128 * 64];
  __shared__ __align__(16) u16 Bs[3][128 * 64];
  GEMM_PROLOG
  GEMM_LOOP3(A, B, K)
#pragma unroll
  for (int i = 0; i < 4; ++i)
#pragma unroll
    for (int j = 0; j < 4; ++j) {
      const int mr = m0 + wm * 64 + i * 16 + g * 4;
      const int nc = n0 + wn * 64 + j * 16 + c15;
#pragma unroll
      for (int r = 0; r < 4; ++r) {
        if (OUT_BF16)
          ((u16*)Cv)[(size_t)(mr + r) * N + nc] = f2b(acc[i][j][r]);
        else
          ((float*)Cv)[(size_t)(mr + r) * N + nc] = acc[i][j][r];
      }
    }
}

// ---------------------------------------------------------------------------
// Fused GEMM2: z=0 -> qraw = qn @ Wqb^T (bf16, N=4096);
//              z=1 -> kv = kvn @ Wkvb^T, scatter into swizzled Kb (K staged
//              via LDS in attn) and PLAIN Vt (V read direct from L2 in attn).
// ---------------------------------------------------------------------------
__global__ __launch_bounds__(256) void gemm2_fused(
    const u16* __restrict__ qn, const u16* __restrict__ Wqbb,
    const u16* __restrict__ kvn, const u16* __restrict__ Wkvbb,
    u16* __restrict__ qraw, char* __restrict__ KbB, char* __restrict__ VtB) {
  __shared__ __align__(16) u16 As[2][128 * 64];
  __shared__ __align__(16) u16 Bs[2][128 * 64];
  const int z = blockIdx.z;
  const u16* A = z ? kvn : qn;
  const u16* B = z ? Wkvbb : Wqbb;
  const int K = z ? 896 : 1024;
  GEMM_PROLOG
  GEMM_LOOP(A, B, K)

  if (z == 0) {
#pragma unroll
    for (int i = 0; i < 4; ++i)
#pragma unroll
      for (int j = 0; j < 4; ++j) {
        const int mr = m0 + wm * 64 + i * 16 + g * 4;
        const int nc = n0 + wn * 64 + j * 16 + c15;
#pragma unroll
        for (int r = 0; r < 4; ++r)
          qraw[(size_t)(mr + r) * 4096 + nc] = f2b(acc[i][j][r]);
      }
  } else {
    const int h = n0 >> 7;  // 128-col tile == one head
#pragma unroll
    for (int i = 0; i < 4; ++i)
#pragma unroll
      for (int j = 0; j < 4; ++j) {
        const int mr = m0 + wm * 64 + i * 16 + g * 4;  // s0 (mult of 4)
        if (wn == 0) {
          const int d = j * 16 + c15;                  // k_nope col (swizzled)
#pragma unroll
          for (int r = 0; r < 4; ++r) {
            const int s = mr + r;
            *(u16*)(KbB + ((size_t)(h * 2048 + s) << 8) +
                    ((2 * d) ^ ((s & 7) << 4))) = f2b(acc[i][j][r]);
          }
        } else {
          const int d = j * 16 + c15;                  // value col (plain)
          u16x4 o;
#pragma unroll
          for (int r = 0; r < 4; ++r) o[r] = f2b(acc[i][j][r]);
          *(u16x4*)(VtB + ((size_t)(h * 64 + d) << 12) + 2 * mr) = o;
        }
      }
  }
}

// ---------------------------------------------------------------------------
// Per-row (C1 in bf16): RMSNorm(q_a)->qn, RMSNorm(ckv)->kvn, RoPE(k_rope)->
// broadcast into Kb[h][s][64:128] (swizzled) for all 32 heads.
// ---------------------------------------------------------------------------
DEVI float block_sum(float v, float* sbuf, int tid) {
#pragma unroll
  for (int o = 32; o; o >>= 1) v += __shfl_xor(v, o, 64);
  __syncthreads();
  if ((tid & 63) == 0) sbuf[tid >> 6] = v;
  __syncthreads();
  return sbuf[0] + sbuf[1] + sbuf[2] + sbuf[3];
}

__global__ __launch_bounds__(256) void norm_rope(const u16* __restrict__ C1b,
    const float* __restrict__ qw, const float* __restrict__ kw,
    const float* __restrict__ cosb, const float* __restrict__ sinb,
    u16* __restrict__ qn, u16* __restrict__ kvn, char* __restrict__ KbB) {
  __shared__ float sbuf[4];
  __shared__ __align__(16) u16 rv[64];
  const int s = blockIdx.x, tid = threadIdx.x;
  const u16* row = C1b + (size_t)s * 2048;

  u16x4 qv4 = *(const u16x4*)(row + tid * 4);
  float q0 = b2f(qv4[0]), q1 = b2f(qv4[1]), q2 = b2f(qv4[2]), q3 = b2f(qv4[3]);
  float ss = q0*q0 + q1*q1 + q2*q2 + q3*q3;
  ss = block_sum(ss, sbuf, tid);
  const float scale = rsqrtf(ss * (1.f / 1024.f) + 1e-6f);
  {
    f32x4 wv = *(const f32x4*)(qw + tid * 4);
    u16x4 o;
    o[0] = f2b(q0 * scale * wv[0]); o[1] = f2b(q1 * scale * wv[1]);
    o[2] = f2b(q2 * scale * wv[2]); o[3] = f2b(q3 * scale * wv[3]);
    *(u16x4*)(qn + (size_t)s * 1024 + tid * 4) = o;
  }

  float ss2 = 0.f;
  float k0 = 0, k1 = 0, k2 = 0, k3 = 0;
  if (tid < 224) {
    u16x4 kv4 = *(const u16x4*)(row + 1024 + tid * 4);
    k0 = b2f(kv4[0]); k1 = b2f(kv4[1]); k2 = b2f(kv4[2]); k3 = b2f(kv4[3]);
    ss2 = k0*k0 + k1*k1 + k2*k2 + k3*k3;
  }
  ss2 = block_sum(ss2, sbuf, tid);
  const float sc2 = rsqrtf(ss2 * (1.f / 896.f) + 1e-6f);
  if (tid < 224) {
    f32x4 wv = *(const f32x4*)(kw + tid * 4);
    u16x4 o;
    o[0] = f2b(k0 * sc2 * wv[0]); o[1] = f2b(k1 * sc2 * wv[1]);
    o[2] = f2b(k2 * sc2 * wv[2]); o[3] = f2b(k3 * sc2 * wv[3]);
    *(u16x4*)(kvn + (size_t)s * 896 + tid * 4) = o;
  }

  if (tid < 64) {
    const int d = tid;
    const float x = b2f(row[1920 + d]);
    const float part = b2f(row[1920 + (d < 32 ? d + 32 : d - 32)]);
    const float cv = cosb[s * 64 + d], sv = sinb[s * 64 + d];
    rv[d] = f2b(d < 32 ? (x * cv - part * sv) : (x * cv + part * sv));
  }
  __syncthreads();
  {
    const int h = tid >> 3, c8 = tid & 7;
    const u16x8 v = *(const u16x8*)&rv[c8 * 8];
    *(u16x8*)(KbB + ((size_t)(h * 2048 + s) << 8) +
              ((128 + c8 * 16) ^ ((s & 7) << 4))) = v;
  }
}

// ---------------------------------------------------------------------------
// Causal flash attention v13 (R9 base + V-direct): 512 blocks (128-row
// q-tile x head), 4 waves, 32 q/wave. K staged via global_load_lds into
// swizzled LDS (dbuf, VMCNT(4) counted pipeline). V read DIRECT from
// L2-resident plain Vt (issued before QK; ~300cyc latency hides under
// QK MFMA + softmax). LDS 32KB. Balanced qb pairs (x,x+8) sum 15, LPT.
// ---------------------------------------------------------------------------
__global__ __launch_bounds__(256) void attn_fwd(
    const u16* __restrict__ Qb, const u16* __restrict__ Kb,
    const u16* __restrict__ Vt, const float* __restrict__ cosb,
    const float* __restrict__ sinb, u16* __restrict__ attnb) {
  __shared__ __align__(16) u16 Klds[2][64 * 128];  // swizzled [kv][128]
  const int tid = threadIdx.x;
  const int lane = tid & 63, w = tid >> 6;
  const int c15 = lane & 15, g = lane >> 4;
  const int orig = blockIdx.x;                 // 512 blocks
  const int xcd = orig & 7, l = orig >> 3;     // 64 per XCD chunk
  const int h = xcd * 4 + (l & 3);
  const int x = l >> 2;                        // 0..15
  const int qb = (x < 8) ? (15 - x) : (x - 8); // pair (x, x+8): qb sums to 15
  const int wmin = qb * 128 + w * 32;          // wave's lowest q row
  const int wmax = wmin + 31;
  const char* KbHB = (const char*)Kb + ((size_t)h << 19);
  const char* VtHB = (const char*)Vt + ((size_t)h << 18);
  const float SC2 = 0.12753860478587782f;  // (HD+MD)^-0.5 * log2(e)

  // Q fragments for 2 q-subtiles (B operand, k=d), scaled, RoPE on d>=64
  s16x8 qf[2][4];
#pragma unroll
  for (int qa = 0; qa < 2; ++qa) {
    const int qrow = wmin + qa * 16 + c15;
    const u16* qp = Qb + (size_t)qrow * 4096 + h * 128;
    u16x8 x0 = *(const u16x8*)(qp + g * 8);
    u16x8 x1 = *(const u16x8*)(qp + 32 + g * 8);
    u16x8 x2 = *(const u16x8*)(qp + 64 + g * 8);
    u16x8 x3 = *(const u16x8*)(qp + 96 + g * 8);
    const float* cb = cosb + (size_t)qrow * 64 + g * 8;
    const float* sb = sinb + (size_t)qrow * 64 + g * 8;
#pragma unroll
    for (int i = 0; i < 8; ++i) {
      qf[qa][0][i] = (short)f2b(b2f(x0[i]) * SC2);
      qf[qa][1][i] = (short)f2b(b2f(x1[i]) * SC2);
      const float f2 = b2f(x2[i]), f3 = b2f(x3[i]);
      qf[qa][2][i] = (short)f2b((f2 * cb[i] - f3 * sb[i]) * SC2);
      qf[qa][3][i] = (short)f2b((f3 * cb[32 + i] + f2 * sb[32 + i]) * SC2);
    }
  }

  const int nt = 2 * qb + 2;
  auto STAGE = [&](int t, int buf) {   // K only: 4 x 16B per thread
    const int kv0 = t << 6;
#pragma unroll
    for (int p = 0; p < 4; ++p) {
      const int c = tid + p * 256;
      gload_lds16(KbHB + ((size_t)(kv0 + (c >> 4)) << 8) + (c & 15) * 16,
                  (char*)Klds[buf] + c * 16);
    }
  };

  f32x4 acc[2][4] = {};
  float m[2] = {-1e9f, -1e9f}, ssum[2] = {0.f, 0.f};

  STAGE(0, 0);

  for (int t = 0; t < nt; ++t) {
    const int cur = t & 1;
    const int kv0 = t << 6;
    if (t + 1 < nt) {
      STAGE(t + 1, cur ^ 1);
      VMCNT(4);      // everything older than the 4 newest loads retired
    } else {
      VMCNT(0);
    }
    SBAR();
    SCHED0();

    if (kv0 <= wmax) {  // wave-uniform skip of fully-masked tiles
      const u16* Kc = Klds[cur];

      // V fragments: direct from L2-resident plain Vt, issued BEFORE QK so
      // latency hides under the QK MFMAs + softmax.
      s16x4 vf[4][4];
#pragma unroll
      for (int dt = 0; dt < 4; ++dt) {
        const char* vp = VtHB + (size_t)(dt * 16 + c15) * 4096 + 2 * (kv0 + g * 4);
#pragma unroll
        for (int ks = 0; ks < 4; ++ks)
          vf[dt][ks] = *(const s16x4*)(vp + ks * 32);
      }

      float pv[2][4][4];
      __builtin_amdgcn_s_setprio(1);
#pragma unroll
      for (int kvh = 0; kvh < 4; ++kvh) {
        s16x8 kf[4];
        const int rb = (kvh * 16 + c15) * 256;
#pragma unroll
        for (int d0 = 0; d0 < 4; ++d0)
          kf[d0] = *(const s16x8*)((const char*)Kc + rb +
                                   ((d0 * 64 + g * 16) ^ ((c15 & 7) << 4)));
#pragma unroll
        for (int qa = 0; qa < 2; ++qa) {
          f32x4 s4 = {};
#pragma unroll
          for (int d0 = 0; d0 < 4; ++d0)
            s4 = __builtin_amdgcn_mfma_f32_16x16x32_bf16(kf[d0], qf[qa][d0], s4, 0, 0, 0);
          pv[qa][kvh][0] = s4[0]; pv[qa][kvh][1] = s4[1];
          pv[qa][kvh][2] = s4[2]; pv[qa][kvh][3] = s4[3];
        }
      }
      __builtin_amdgcn_s_setprio(0);

      if (kv0 + 63 > wmin) {  // diagonal region for this wave
#pragma unroll
        for (int qa = 0; qa < 2; ++qa) {
          const int qrow = wmin + qa * 16 + c15;
#pragma unroll
          for (int kvh = 0; kvh < 4; ++kvh)
#pragma unroll
            for (int r = 0; r < 4; ++r) {
              const int kv = kv0 + kvh * 16 + g * 4 + r;
              if (kv > qrow) pv[qa][kvh][r] = -1e9f;
            }
        }
      }

      s16x4 pB[2][4];
#pragma unroll
      for (int qa = 0; qa < 2; ++qa) {
        // per-lane partial max; full cross-lane reduce only when needed
        float pml = -1e9f;
#pragma unroll
        for (int kvh = 0; kvh < 4; ++kvh)
#pragma unroll
          for (int r = 0; r < 4; ++r) pml = fmaxf(pml, pv[qa][kvh][r]);
        if (!__all(pml - m[qa] <= 8.f)) {     // pm-defer (T13 extended)
          float pm = fmaxf(pml, __shfl_xor(pml, 16, 64));
          pm = fmaxf(pm, __shfl_xor(pm, 32, 64));
          const float mnew = fmaxf(m[qa], pm);
          const float alpha = exp2a(m[qa] - mnew);
          ssum[qa] *= alpha;
#pragma unroll
          for (int dt = 0; dt < 4; ++dt) acc[qa][dt] *= alpha;
          m[qa] = mnew;
        }
#pragma unroll
        for (int kvh = 0; kvh < 4; ++kvh)
#pragma unroll
          for (int r = 0; r < 4; ++r) {
            const float p = exp2a(pv[qa][kvh][r] - m[qa]);
            pv[qa][kvh][r] = p;
            ssum[qa] += p;
          }
#pragma unroll
        for (int ks = 0; ks < 4; ++ks) {
          u32x2 pw;
          pw[0] = cvtpk(pv[qa][ks][0], pv[qa][ks][1]);
          pw[1] = cvtpk(pv[qa][ks][2], pv[qa][ks][3]);
          pB[qa][ks] = __builtin_bit_cast(s16x4, pw);
        }
      }

      __builtin_amdgcn_s_setprio(1);
#pragma unroll
      for (int dt = 0; dt < 4; ++dt) {
#pragma unroll
        for (int ks = 0; ks < 4; ++ks) {
          acc[0][dt] = mfma16(vf[dt][ks], pB[0][ks], acc[0][dt]);
          acc[1][dt] = mfma16(vf[dt][ks], pB[1][ks], acc[1][dt]);
        }
      }
      __builtin_amdgcn_s_setprio(0);
    }
    SBAR();
    SCHED0();
  }

#pragma unroll
  for (int qa = 0; qa < 2; ++qa) {
    float sv = ssum[qa];
    sv += __shfl_xor(sv, 16, 64);
    sv += __shfl_xor(sv, 32, 64);
    const float inv = 1.f / sv;
    const int qrow = wmin + qa * 16 + c15;
#pragma unroll
    for (int dt = 0; dt < 4; ++dt) {
      u16x4 o;
#pragma unroll
      for (int r = 0; r < 4; ++r) o[r] = f2b(acc[qa][dt][r] * inv);
      *(u16x4*)(attnb + (size_t)qrow * 2048 + h * 64 + dt * 16 + g * 4) = o;
    }
  }
}

// ---------------------------------------------------------------------------
extern "C" void kernel_launch(void* const* d_in, const int* in_sizes, int n_in,
                              void* d_out, int out_size, void* d_ws, size_t ws_size,
                              hipStream_t stream) {
  const float* X    = (const float*)d_in[0];
  const float* cosb = (const float*)d_in[1];
  const float* sinb = (const float*)d_in[2];
  const float* Wqa  = (const float*)d_in[3];
  const float* qlnw = (const float*)d_in[4];
  const float* Wqb  = (const float*)d_in[5];
  const float* Wkva = (const float*)d_in[6];
  const float* klnw = (const float*)d_in[7];
  const float* Wkvb = (const float*)d_in[8];
  const float* Wo   = (const float*)d_in[9];
  float* out = (float*)d_out;
  char* ws = (char*)d_ws;

  // workspace layout (bytes); total 96 MiB
  u16*   Xb     = (u16*)(ws + 0);          // [0,8M)     dies after GEMM1
  u16*   W1     = (u16*)(ws + 8388608);    // [8,16M)    dies after GEMM1
  u16*   C1b    = (u16*)(ws + 16777216);   // [16,24M)   bf16, dies after norm
  u16*   qn     = (u16*)(ws + 33554432);   // [32,36M)
  u16*   kvn    = (u16*)(ws + 37748736);   // [36,39.5M)
  u16*   Wqbb   = (u16*)(ws + 41943040);   // [40,48M)
  u16*   Wkvbb  = (u16*)(ws + 50331648);   // [48,55M)
  u16*   qraw_b = (u16*)(ws + 0);          // [0,16M)  overlays Xb+W1
  u16*   Kb     = (u16*)(ws + 58720256);   // [56,72M)  32h x 2048 x 256B swz
  u16*   VtG    = (u16*)(ws + 75497472);   // [72,80M)  32h x 64 x 4096B plain
  u16*   attnb  = (u16*)(ws + 83886080);   // [80,88M)
  u16*   Wob    = (u16*)(ws + 92274688);   // [88,96M)

  // 1. all f32->bf16 conversions in one dispatch
  cvt_all<<<2048, 256, 0, stream>>>(X, Wqa, Wkva, Wqb, Wkvb, Wo,
                                    Xb, W1, Wqbb, Wkvbb, Wob);

  // 2. C1 = X @ [Wqa;Wkva]^T  (bf16 out)
  gemm_out<1><<<dim3(16, 16), 256, 0, stream>>>(Xb, W1, C1b, 2048, 2048, 2048);

  // 3. RMSNorm + roped-k broadcast into Kb[..][64:128]
  norm_rope<<<2048, 256, 0, stream>>>(C1b, qlnw, klnw, cosb, sinb, qn, kvn, (char*)Kb);

  // 4. fused: qraw_b = qn @ Wqb^T  and  {Kb,Vt} <- kvn @ Wkvb^T
  gemm2_fused<<<dim3(32, 16, 2), 256, 0, stream>>>(qn, Wqbb, kvn, Wkvbb,
                                                   qraw_b, (char*)Kb, (char*)VtG);

  // 5. causal attention (K via LDS, V direct from L2)
  attn_fwd<<<512, 256, 0, stream>>>(qraw_b, Kb, VtG, cosb, sinb, attnb);

  // 6. out = attn @ Wo^T  (f32 out)
  gemm_out<0><<<dim3(16, 16), 256, 0, stream>>>(attnb, Wob, out, 2048, 2048, 2048);
}

// Round 16
// 170.113 us; speedup vs baseline: 1.3988x; 1.1878x over previous
//
#include <hip/hip_runtime.h>
#include <stdint.h>

typedef unsigned short u16;
typedef __attribute__((ext_vector_type(4))) float f32x4;
typedef __attribute__((ext_vector_type(4))) unsigned short u16x4;
typedef __attribute__((ext_vector_type(8))) unsigned short u16x8;
typedef __attribute__((ext_vector_type(8))) short s16x8;
typedef __attribute__((ext_vector_type(4))) short s16x4;
typedef __attribute__((ext_vector_type(2))) unsigned int u32x2;

#define DEVI static __device__ __forceinline__

// counted-vmcnt sync primitives (T4)
#define VMCNT(n) asm volatile("s_waitcnt vmcnt(" #n ")" ::: "memory")
#define SBAR() __builtin_amdgcn_s_barrier()
#define SCHED0() __builtin_amdgcn_sched_barrier(0)

// f32 -> bf16 round-to-nearest-even
DEVI u16 f2b(float f) {
  union { float f; unsigned u; } v; v.f = f;
  unsigned r = v.u + 0x7fffu + ((v.u >> 16) & 1u);
  return (u16)(r >> 16);
}
DEVI float b2f(u16 b) {
  union { unsigned u; float f; } v; v.u = ((unsigned)b) << 16;
  return v.f;
}

// async global->LDS, 16B per lane. LDS dest must be wave-uniform base + lane*16.
DEVI void gload_lds16(const void* gptr, void* lptr) {
  typedef const __attribute__((address_space(1))) unsigned gq;
  typedef __attribute__((address_space(3))) unsigned lq;
  __builtin_amdgcn_global_load_lds((gq*)(uintptr_t)gptr,
                                   (lq*)(uint32_t)(uintptr_t)lptr, 16, 0, 0);
}

// v_cvt_pk_bf16_f32: lo=bf16(a), hi=bf16(b)
DEVI unsigned cvtpk(float a, float b) {
  unsigned d;
  asm("v_cvt_pk_bf16_f32 %0, %1, %2" : "=v"(d) : "v"(a), "v"(b));
  return d;
}
// 16x16x16 bf16 MFMA
DEVI f32x4 mfma16(s16x4 a, s16x4 b, f32x4 c) {
  f32x4 d;
  asm("v_mfma_f32_16x16x16_bf16 %0, %1, %2, %3" : "=v"(d) : "v"(a), "v"(b), "v"(c));
  return d;
}
// v_exp_f32 is exp2
DEVI float exp2a(float x) {
  float d;
  asm("v_exp_f32 %0, %1" : "=v"(d) : "v"(x));
  return d;
}

// ---------------------------------------------------------------------------
// All f32 -> bf16 conversions in one dispatch (6 segments, hardcoded bounds).
// ---------------------------------------------------------------------------
__global__ __launch_bounds__(256) void cvt_all(
    const float* __restrict__ X, const float* __restrict__ Wqa,
    const float* __restrict__ Wkva, const float* __restrict__ Wqb,
    const float* __restrict__ Wkvb, const float* __restrict__ Wo,
    u16* __restrict__ Xb, u16* __restrict__ W1, u16* __restrict__ Wqbb,
    u16* __restrict__ Wkvbb, u16* __restrict__ Wob) {
  int i = blockIdx.x * 256 + threadIdx.x;
  const int stride = gridDim.x * 256;
  for (; i < 5079040; i += stride) {   // units of f32x4
    const float* s; u16* d; int j;
    if (i < 1572864) {
      if (i < 1048576) { s = X; d = Xb; j = i; }
      else             { s = Wqa; d = W1; j = i - 1048576; }
    } else if (i < 3112960) {
      if (i < 2064384) { s = Wkva; d = W1 + 1024 * 2048; j = i - 1572864; }
      else             { s = Wqb; d = Wqbb; j = i - 2064384; }
    } else {
      if (i < 4030464) { s = Wkvb; d = Wkvbb; j = i - 3112960; }
      else             { s = Wo; d = Wob; j = i - 4030464; }
    }
    f32x4 v = *(const f32x4*)(s + (size_t)j * 4);
    u16x4 o;
    o[0] = f2b(v[0]); o[1] = f2b(v[1]); o[2] = f2b(v[2]); o[3] = f2b(v[3]);
    *(u16x4*)(d + (size_t)j * 4) = o;
  }
}

// ---------------------------------------------------------------------------
// GEMM core: 128x128 tile, BK=64, 4 waves (2x2), T2 swizzle, T4 counted vmcnt.
// gemm_out: depth-3 pipeline; gemm2_fused: depth-2.
// ---------------------------------------------------------------------------
#define GEMM_STAGE(AP, BP, KK, k0, buf)                                        \
  {                                                                            \
    _Pragma("unroll") for (int p = 0; p < 4; ++p) {                            \
      const int c = tid + p * 256;                                             \
      const int row = c >> 3, j = c & 7;                                       \
      gload_lds16(AP + (size_t)(m0 + row) * (KK) + (k0) + ((j ^ (row & 7)) * 8), \
                  &As[buf][c * 8]);                                            \
    }                                                                          \
    _Pragma("unroll") for (int p = 0; p < 4; ++p) {                            \
      const int c = tid + p * 256;                                             \
      const int row = c >> 3, j = c & 7;                                       \
      gload_lds16(BP + (size_t)(n0 + row) * (KK) + (k0) + ((j ^ (row & 7)) * 8), \
                  &Bs[buf][c * 8]);                                            \
    }                                                                          \
  }

#define GEMM_COMPUTE(cur)                                                      \
  _Pragma("unroll") for (int kk = 0; kk < 64; kk += 32) {                      \
    s16x8 af[4], bfr[4];                                                       \
    _Pragma("unroll") for (int i = 0; i < 4; ++i) {                            \
      const int rA = wm * 64 + i * 16 + c15;                                   \
      af[i] = *(const s16x8*)((const char*)&As[cur][0] + rA * 128 +            \
                              (((kk + g * 8) * 2) ^ ((rA & 7) << 4)));         \
    }                                                                          \
    _Pragma("unroll") for (int i = 0; i < 4; ++i) {                            \
      const int rB = wn * 64 + i * 16 + c15;                                   \
      bfr[i] = *(const s16x8*)((const char*)&Bs[cur][0] + rB * 128 +           \
                               (((kk + g * 8) * 2) ^ ((rB & 7) << 4)));        \
    }                                                                          \
    _Pragma("unroll") for (int i = 0; i < 4; ++i)                              \
      _Pragma("unroll") for (int j = 0; j < 4; ++j)                            \
        acc[i][j] = __builtin_amdgcn_mfma_f32_16x16x32_bf16(af[i], bfr[j],     \
                                                            acc[i][j], 0, 0, 0); \
  }

#define GEMM_PROLOG                                                            \
  const int tid = threadIdx.x;                                                 \
  const int lane = tid & 63, w = tid >> 6;                                     \
  const int wm = w >> 1, wn = w & 1;                                           \
  const int c15 = lane & 15, g = lane >> 4;                                    \
  const int m0 = blockIdx.y * 128, n0 = blockIdx.x * 128;                      \
  f32x4 acc[4][4] = {};

// depth-2 (gemm2_fused)
#define GEMM_LOOP(AP, BP, KK)                                                  \
  GEMM_STAGE(AP, BP, KK, 0, 0);                                                \
  const int nk = (KK) >> 6;                                                    \
  for (int kt = 0; kt < nk; ++kt) {                                            \
    const int cur = kt & 1;                                                    \
    if (kt + 1 < nk) {                                                         \
      GEMM_STAGE(AP, BP, KK, (kt + 1) << 6, cur ^ 1);                          \
      VMCNT(8);                                                                \
    } else {                                                                   \
      VMCNT(0);                                                                \
    }                                                                          \
    SBAR(); SCHED0();                                                          \
    GEMM_COMPUTE(cur);                                                         \
    SBAR(); SCHED0();                                                          \
  }

// depth-3 (gemm_out; requires nk >= 2)
#define GEMM_LOOP3(AP, BP, KK)                                                 \
  GEMM_STAGE(AP, BP, KK, 0, 0);                                                \
  GEMM_STAGE(AP, BP, KK, 64, 1);                                               \
  const int nk = (KK) >> 6;                                                    \
  int bufc = 0;                                                                \
  for (int kt = 0; kt < nk; ++kt) {                                            \
    const int nxt = (bufc + 2 >= 3) ? bufc - 1 : bufc + 2;                     \
    if (kt + 2 < nk) {                                                         \
      GEMM_STAGE(AP, BP, KK, (kt + 2) << 6, nxt);                              \
      VMCNT(16);                                                               \
    } else if (kt + 1 < nk) {                                                  \
      VMCNT(8);                                                                \
    } else {                                                                   \
      VMCNT(0);                                                                \
    }                                                                          \
    SBAR(); SCHED0();                                                          \
    GEMM_COMPUTE(bufc);                                                        \
    SBAR(); SCHED0();                                                          \
    bufc = (bufc + 1 == 3) ? 0 : bufc + 1;                                     \
  }

// GEMM: OUT_BF16=1 writes u16, else f32.
template <int OUT_BF16>
__global__ __launch_bounds__(256) void gemm_out(const u16* __restrict__ A,
                                                const u16* __restrict__ B,
                                                void* __restrict__ Cv,
                                                int M, int N, int K) {
  __shared__ __align__(16) u16 As[3][128 * 64];
  __shared__ __align__(16) u16 Bs[3][128 * 64];
  GEMM_PROLOG
  GEMM_LOOP3(A, B, K)
#pragma unroll
  for (int i = 0; i < 4; ++i)
#pragma unroll
    for (int j = 0; j < 4; ++j) {
      const int mr = m0 + wm * 64 + i * 16 + g * 4;
      const int nc = n0 + wn * 64 + j * 16 + c15;
#pragma unroll
      for (int r = 0; r < 4; ++r) {
        if (OUT_BF16)
          ((u16*)Cv)[(size_t)(mr + r) * N + nc] = f2b(acc[i][j][r]);
        else
          ((float*)Cv)[(size_t)(mr + r) * N + nc] = acc[i][j][r];
      }
    }
}

// ---------------------------------------------------------------------------
// Fused GEMM2: z=0 -> qraw = qn @ Wqb^T (bf16, N=4096);
//              z=1 -> kv = kvn @ Wkvb^T, scatter into swizzled Kb/Vt.
// ---------------------------------------------------------------------------
__global__ __launch_bounds__(256) void gemm2_fused(
    const u16* __restrict__ qn, const u16* __restrict__ Wqbb,
    const u16* __restrict__ kvn, const u16* __restrict__ Wkvbb,
    u16* __restrict__ qraw, char* __restrict__ KbB, char* __restrict__ VtB) {
  __shared__ __align__(16) u16 As[2][128 * 64];
  __shared__ __align__(16) u16 Bs[2][128 * 64];
  const int z = blockIdx.z;
  const u16* A = z ? kvn : qn;
  const u16* B = z ? Wkvbb : Wqbb;
  const int K = z ? 896 : 1024;
  GEMM_PROLOG
  GEMM_LOOP(A, B, K)

  if (z == 0) {
#pragma unroll
    for (int i = 0; i < 4; ++i)
#pragma unroll
      for (int j = 0; j < 4; ++j) {
        const int mr = m0 + wm * 64 + i * 16 + g * 4;
        const int nc = n0 + wn * 64 + j * 16 + c15;
#pragma unroll
        for (int r = 0; r < 4; ++r)
          qraw[(size_t)(mr + r) * 4096 + nc] = f2b(acc[i][j][r]);
      }
  } else {
    const int h = n0 >> 7;  // 128-col tile == one head
#pragma unroll
    for (int i = 0; i < 4; ++i)
#pragma unroll
      for (int j = 0; j < 4; ++j) {
        const int mr = m0 + wm * 64 + i * 16 + g * 4;  // s0 (mult of 4)
        if (wn == 0) {
          const int d = j * 16 + c15;                  // k_nope col
#pragma unroll
          for (int r = 0; r < 4; ++r) {
            const int s = mr + r;
            *(u16*)(KbB + ((size_t)(h * 2048 + s) << 8) +
                    ((2 * d) ^ ((s & 7) << 4))) = f2b(acc[i][j][r]);
          }
        } else {
          const int d = j * 16 + c15;                  // value col (0..63)
          u16x4 o;
#pragma unroll
          for (int r = 0; r < 4; ++r) o[r] = f2b(acc[i][j][r]);
          *(u16x4*)(VtB + ((size_t)(h * 64 + d) << 12) +
                    ((2 * mr) ^ ((d & 7) << 4))) = o;
        }
      }
  }
}

// ---------------------------------------------------------------------------
// Per-row (C1 in bf16): RMSNorm(q_a)->qn, RMSNorm(ckv)->kvn, RoPE(k_rope)->
// broadcast into Kb[h][s][64:128] (swizzled) for all 32 heads.
// ---------------------------------------------------------------------------
DEVI float block_sum(float v, float* sbuf, int tid) {
#pragma unroll
  for (int o = 32; o; o >>= 1) v += __shfl_xor(v, o, 64);
  __syncthreads();
  if ((tid & 63) == 0) sbuf[tid >> 6] = v;
  __syncthreads();
  return sbuf[0] + sbuf[1] + sbuf[2] + sbuf[3];
}

__global__ __launch_bounds__(256) void norm_rope(const u16* __restrict__ C1b,
    const float* __restrict__ qw, const float* __restrict__ kw,
    const float* __restrict__ cosb, const float* __restrict__ sinb,
    u16* __restrict__ qn, u16* __restrict__ kvn, char* __restrict__ KbB) {
  __shared__ float sbuf[4];
  __shared__ __align__(16) u16 rv[64];
  const int s = blockIdx.x, tid = threadIdx.x;
  const u16* row = C1b + (size_t)s * 2048;

  u16x4 qv4 = *(const u16x4*)(row + tid * 4);
  float q0 = b2f(qv4[0]), q1 = b2f(qv4[1]), q2 = b2f(qv4[2]), q3 = b2f(qv4[3]);
  float ss = q0*q0 + q1*q1 + q2*q2 + q3*q3;
  ss = block_sum(ss, sbuf, tid);
  const float scale = rsqrtf(ss * (1.f / 1024.f) + 1e-6f);
  {
    f32x4 wv = *(const f32x4*)(qw + tid * 4);
    u16x4 o;
    o[0] = f2b(q0 * scale * wv[0]); o[1] = f2b(q1 * scale * wv[1]);
    o[2] = f2b(q2 * scale * wv[2]); o[3] = f2b(q3 * scale * wv[3]);
    *(u16x4*)(qn + (size_t)s * 1024 + tid * 4) = o;
  }

  float ss2 = 0.f;
  float k0 = 0, k1 = 0, k2 = 0, k3 = 0;
  if (tid < 224) {
    u16x4 kv4 = *(const u16x4*)(row + 1024 + tid * 4);
    k0 = b2f(kv4[0]); k1 = b2f(kv4[1]); k2 = b2f(kv4[2]); k3 = b2f(kv4[3]);
    ss2 = k0*k0 + k1*k1 + k2*k2 + k3*k3;
  }
  ss2 = block_sum(ss2, sbuf, tid);
  const float sc2 = rsqrtf(ss2 * (1.f / 896.f) + 1e-6f);
  if (tid < 224) {
    f32x4 wv = *(const f32x4*)(kw + tid * 4);
    u16x4 o;
    o[0] = f2b(k0 * sc2 * wv[0]); o[1] = f2b(k1 * sc2 * wv[1]);
    o[2] = f2b(k2 * sc2 * wv[2]); o[3] = f2b(k3 * sc2 * wv[3]);
    *(u16x4*)(kvn + (size_t)s * 896 + tid * 4) = o;
  }

  if (tid < 64) {
    const int d = tid;
    const float x = b2f(row[1920 + d]);
    const float part = b2f(row[1920 + (d < 32 ? d + 32 : d - 32)]);
    const float cv = cosb[s * 64 + d], sv = sinb[s * 64 + d];
    rv[d] = f2b(d < 32 ? (x * cv - part * sv) : (x * cv + part * sv));
  }
  __syncthreads();
  {
    const int h = tid >> 3, c8 = tid & 7;
    const u16x8 v = *(const u16x8*)&rv[c8 * 8];
    *(u16x8*)(KbB + ((size_t)(h * 2048 + s) << 8) +
              ((128 + c8 * 16) ^ ((s & 7) << 4))) = v;
  }
}

// ---------------------------------------------------------------------------
// Causal flash attention (R9 config, best-known): 512 blocks (128-row q-tile
// x head), 4 waves, 32 q/wave. K+V staged via global_load_lds into swizzled
// LDS (dbuf, VMCNT(6) counted pipeline). Balanced qb pairs (x,x+8) sum 15,
// LPT. exp2 softmax, per-lane pm-defer (T13 ext), deferred ssum reduce.
// ---------------------------------------------------------------------------
__global__ __launch_bounds__(256) void attn_fwd(
    const u16* __restrict__ Qb, const u16* __restrict__ Kb,
    const u16* __restrict__ Vt, const float* __restrict__ cosb,
    const float* __restrict__ sinb, u16* __restrict__ attnb) {
  __shared__ __align__(16) u16 Klds[2][64 * 128];  // swizzled [kv][128]
  __shared__ __align__(16) u16 Vlds[2][64 * 64];   // swizzled [d][kv]
  const int tid = threadIdx.x;
  const int lane = tid & 63, w = tid >> 6;
  const int c15 = lane & 15, g = lane >> 4;
  const int orig = blockIdx.x;                 // 512 blocks
  const int xcd = orig & 7, l = orig >> 3;     // 64 per XCD chunk
  const int h = xcd * 4 + (l & 3);
  const int x = l >> 2;                        // 0..15
  const int qb = (x < 8) ? (15 - x) : (x - 8); // pair (x, x+8): qb sums to 15
  const int wmin = qb * 128 + w * 32;          // wave's lowest q row
  const int wmax = wmin + 31;
  const char* KbHB = (const char*)Kb + ((size_t)h << 19);
  const char* VtHB = (const char*)Vt + ((size_t)h << 18);
  const float SC2 = 0.12753860478587782f;  // (HD+MD)^-0.5 * log2(e)

  // Q fragments for 2 q-subtiles (B operand, k=d), scaled, RoPE on d>=64
  s16x8 qf[2][4];
#pragma unroll
  for (int qa = 0; qa < 2; ++qa) {
    const int qrow = wmin + qa * 16 + c15;
    const u16* qp = Qb + (size_t)qrow * 4096 + h * 128;
    u16x8 x0 = *(const u16x8*)(qp + g * 8);
    u16x8 x1 = *(const u16x8*)(qp + 32 + g * 8);
    u16x8 x2 = *(const u16x8*)(qp + 64 + g * 8);
    u16x8 x3 = *(const u16x8*)(qp + 96 + g * 8);
    const float* cb = cosb + (size_t)qrow * 64 + g * 8;
    const float* sb = sinb + (size_t)qrow * 64 + g * 8;
#pragma unroll
    for (int i = 0; i < 8; ++i) {
      qf[qa][0][i] = (short)f2b(b2f(x0[i]) * SC2);
      qf[qa][1][i] = (short)f2b(b2f(x1[i]) * SC2);
      const float f2 = b2f(x2[i]), f3 = b2f(x3[i]);
      qf[qa][2][i] = (short)f2b((f2 * cb[i] - f3 * sb[i]) * SC2);
      qf[qa][3][i] = (short)f2b((f3 * cb[32 + i] + f2 * sb[32 + i]) * SC2);
    }
  }

  const int nt = 2 * qb + 2;
  auto STAGE = [&](int t, int buf) {
    const int kv0 = t << 6;
#pragma unroll
    for (int p = 0; p < 4; ++p) {
      const int c = tid + p * 256;
      gload_lds16(KbHB + ((size_t)(kv0 + (c >> 4)) << 8) + (c & 15) * 16,
                  (char*)Klds[buf] + c * 16);
    }
#pragma unroll
    for (int p = 0; p < 2; ++p) {
      const int c = tid + p * 256;
      gload_lds16(VtHB + ((size_t)(c >> 3) << 12) + 2 * kv0 + (c & 7) * 16,
                  (char*)Vlds[buf] + c * 16);
    }
  };

  f32x4 acc[2][4] = {};
  float m[2] = {-1e9f, -1e9f}, ssum[2] = {0.f, 0.f};

  STAGE(0, 0);

  for (int t = 0; t < nt; ++t) {
    const int cur = t & 1;
    const int kv0 = t << 6;
    if (t + 1 < nt) {
      STAGE(t + 1, cur ^ 1);
      VMCNT(6);      // own stage(t) landed; stage(t+1)'s 6 stay in flight
    } else {
      VMCNT(0);
    }
    SBAR();
    SCHED0();

    if (kv0 <= wmax) {  // wave-uniform skip of fully-masked tiles
      const u16* Kc = Klds[cur];
      const u16* Vc = Vlds[cur];

      float pv[2][4][4];
      __builtin_amdgcn_s_setprio(1);
#pragma unroll
      for (int kvh = 0; kvh < 4; ++kvh) {
        s16x8 kf[4];
        const int rb = (kvh * 16 + c15) * 256;
#pragma unroll
        for (int d0 = 0; d0 < 4; ++d0)
          kf[d0] = *(const s16x8*)((const char*)Kc + rb +
                                   ((d0 * 64 + g * 16) ^ ((c15 & 7) << 4)));
#pragma unroll
        for (int qa = 0; qa < 2; ++qa) {
          f32x4 s4 = {};
#pragma unroll
          for (int d0 = 0; d0 < 4; ++d0)
            s4 = __builtin_amdgcn_mfma_f32_16x16x32_bf16(kf[d0], qf[qa][d0], s4, 0, 0, 0);
          pv[qa][kvh][0] = s4[0]; pv[qa][kvh][1] = s4[1];
          pv[qa][kvh][2] = s4[2]; pv[qa][kvh][3] = s4[3];
        }
      }
      __builtin_amdgcn_s_setprio(0);

      if (kv0 + 63 > wmin) {  // diagonal region for this wave
#pragma unroll
        for (int qa = 0; qa < 2; ++qa) {
          const int qrow = wmin + qa * 16 + c15;
#pragma unroll
          for (int kvh = 0; kvh < 4; ++kvh)
#pragma unroll
            for (int r = 0; r < 4; ++r) {
              const int kv = kv0 + kvh * 16 + g * 4 + r;
              if (kv > qrow) pv[qa][kvh][r] = -1e9f;
            }
        }
      }

      s16x4 pB[2][4];
#pragma unroll
      for (int qa = 0; qa < 2; ++qa) {
        // per-lane partial max; full cross-lane reduce only when needed
        float pml = -1e9f;
#pragma unroll
        for (int kvh = 0; kvh < 4; ++kvh)
#pragma unroll
          for (int r = 0; r < 4; ++r) pml = fmaxf(pml, pv[qa][kvh][r]);
        if (!__all(pml - m[qa] <= 8.f)) {     // pm-defer (T13 extended)
          float pm = fmaxf(pml, __shfl_xor(pml, 16, 64));
          pm = fmaxf(pm, __shfl_xor(pm, 32, 64));
          const float mnew = fmaxf(m[qa], pm);
          const float alpha = exp2a(m[qa] - mnew);
          ssum[qa] *= alpha;
#pragma unroll
          for (int dt = 0; dt < 4; ++dt) acc[qa][dt] *= alpha;
          m[qa] = mnew;
        }
#pragma unroll
        for (int kvh = 0; kvh < 4; ++kvh)
#pragma unroll
          for (int r = 0; r < 4; ++r) {
            const float p = exp2a(pv[qa][kvh][r] - m[qa]);
            pv[qa][kvh][r] = p;
            ssum[qa] += p;
          }
#pragma unroll
        for (int ks = 0; ks < 4; ++ks) {
          u32x2 pw;
          pw[0] = cvtpk(pv[qa][ks][0], pv[qa][ks][1]);
          pw[1] = cvtpk(pv[qa][ks][2], pv[qa][ks][3]);
          pB[qa][ks] = __builtin_bit_cast(s16x4, pw);
        }
      }

      __builtin_amdgcn_s_setprio(1);
#pragma unroll
      for (int dt = 0; dt < 4; ++dt) {
        const int rb2 = (dt * 16 + c15) * 128;
#pragma unroll
        for (int ks = 0; ks < 4; ++ks) {
          s16x4 vf = *(const s16x4*)((const char*)Vc + rb2 +
                                     ((ks * 32 + g * 8) ^ ((c15 & 7) << 4)));
          acc[0][dt] = mfma16(vf, pB[0][ks], acc[0][dt]);
          acc[1][dt] = mfma16(vf, pB[1][ks], acc[1][dt]);
        }
      }
      __builtin_amdgcn_s_setprio(0);
    }
    SBAR();
    SCHED0();
  }

#pragma unroll
  for (int qa = 0; qa < 2; ++qa) {
    float sv = ssum[qa];
    sv += __shfl_xor(sv, 16, 64);
    sv += __shfl_xor(sv, 32, 64);
    const float inv = 1.f / sv;
    const int qrow = wmin + qa * 16 + c15;
#pragma unroll
    for (int dt = 0; dt < 4; ++dt) {
      u16x4 o;
#pragma unroll
      for (int r = 0; r < 4; ++r) o[r] = f2b(acc[qa][dt][r] * inv);
      *(u16x4*)(attnb + (size_t)qrow * 2048 + h * 64 + dt * 16 + g * 4) = o;
    }
  }
}

// ---------------------------------------------------------------------------
extern "C" void kernel_launch(void* const* d_in, const int* in_sizes, int n_in,
                              void* d_out, int out_size, void* d_ws, size_t ws_size,
                              hipStream_t stream) {
  const float* X    = (const float*)d_in[0];
  const float* cosb = (const float*)d_in[1];
  const float* sinb = (const float*)d_in[2];
  const float* Wqa  = (const float*)d_in[3];
  const float* qlnw = (const float*)d_in[4];
  const float* Wqb  = (const float*)d_in[5];
  const float* Wkva = (const float*)d_in[6];
  const float* klnw = (const float*)d_in[7];
  const float* Wkvb = (const float*)d_in[8];
  const float* Wo   = (const float*)d_in[9];
  float* out = (float*)d_out;
  char* ws = (char*)d_ws;

  // workspace layout (bytes); total 96 MiB
  u16*   Xb     = (u16*)(ws + 0);          // [0,8M)     dies after GEMM1
  u16*   W1     = (u16*)(ws + 8388608);    // [8,16M)    dies after GEMM1
  u16*   C1b    = (u16*)(ws + 16777216);   // [16,24M)   bf16, dies after norm
  u16*   qn     = (u16*)(ws + 33554432);   // [32,36M)
  u16*   kvn    = (u16*)(ws + 37748736);   // [36,39.5M)
  u16*   Wqbb   = (u16*)(ws + 41943040);   // [40,48M)
  u16*   Wkvbb  = (u16*)(ws + 50331648);   // [48,55M)
  u16*   qraw_b = (u16*)(ws + 0);          // [0,16M)  overlays Xb+W1
  u16*   Kb     = (u16*)(ws + 58720256);   // [56,72M)  32h x 2048 x 256B swz
  u16*   VtG    = (u16*)(ws + 75497472);   // [72,80M)  32h x 64 x 4096B swz
  u16*   attnb  = (u16*)(ws + 83886080);   // [80,88M)
  u16*   Wob    = (u16*)(ws + 92274688);   // [88,96M)

  // 1. all f32->bf16 conversions in one dispatch
  cvt_all<<<2048, 256, 0, stream>>>(X, Wqa, Wkva, Wqb, Wkvb, Wo,
                                    Xb, W1, Wqbb, Wkvbb, Wob);

  // 2. C1 = X @ [Wqa;Wkva]^T  (bf16 out)
  gemm_out<1><<<dim3(16, 16), 256, 0, stream>>>(Xb, W1, C1b, 2048, 2048, 2048);

  // 3. RMSNorm + roped-k broadcast into Kb[..][64:128]
  norm_rope<<<2048, 256, 0, stream>>>(C1b, qlnw, klnw, cosb, sinb, qn, kvn, (char*)Kb);

  // 4. fused: qraw_b = qn @ Wqb^T  and  {Kb,Vt} <- kvn @ Wkvb^T
  gemm2_fused<<<dim3(32, 16, 2), 256, 0, stream>>>(qn, Wqbb, kvn, Wkvbb,
                                                   qraw_b, (char*)Kb, (char*)VtG);

  // 5. causal attention (balanced qb pairs)
  attn_fwd<<<512, 256, 0, stream>>>(qraw_b, Kb, VtG, cosb, sinb, attnb);

  // 6. out = attn @ Wo^T  (f32 out)
  gemm_out<0><<<dim3(16, 16), 256, 0, stream>>>(attnb, Wob, out, 2048, 2048, 2048);
}